// Round 16
// baseline (80.383 us; speedup 1.0000x reference)
//
#include <hip/hip_runtime.h>
#include <hip/hip_bf16.h>

#define EMB 64

typedef __attribute__((ext_vector_type(8))) short short8;
typedef __attribute__((ext_vector_type(8))) __bf16 bf16x8;
typedef __attribute__((ext_vector_type(4))) float f32x4;

__device__ inline f32x4 mfma16x16x32(short8 a, short8 b, f32x4 c) {
  return __builtin_amdgcn_mfma_f32_16x16x32_bf16(
      __builtin_bit_cast(bf16x8, a), __builtin_bit_cast(bf16x8, b), c, 0, 0, 0);
}

// Raw v_exp_f32 (2^x). OCML exp2f/__expf are multi-instr expansions (r2-r4).
#define EXP2_HW __builtin_amdgcn_exp2f
#define C5LOG2E 7.213475204444817f  // 5 * log2(e)

// prep: 512 blocks x 16 rows, 16-lane-group float4 layout (r11-proven).
// Also: clears the 6250-word global dedup bitmap (blocks 0..24) and resets
// gemm's done-counter — stream order makes both safe (gemm scatters later).
__global__ __launch_bounds__(256) void prep_kernel(
    const int* __restrict__ user, const int* __restrict__ pos,
    const float* __restrict__ uw, const float* __restrict__ iw,
    __hip_bfloat16* __restrict__ u_bf, __hip_bfloat16* __restrict__ p_bf,
    float* __restrict__ up_p, unsigned int* __restrict__ bitmap,
    unsigned int* __restrict__ done_cnt)
{
  const int tid  = threadIdx.x;
  const int wave = tid >> 6;
  const int lane = tid & 63;
  const int e    = lane & 15;
  const int row  = blockIdx.x * 16 + wave * 4 + (lane >> 4);

  {
    const int ci = blockIdx.x * 256 + tid;
    if (ci < 6250) bitmap[ci] = 0u;
    if (ci == 6250) *done_cnt = 0u;   // block 24 lane 106 — any single thread
  }

  const int uidx = user[row];
  const int pidx = pos[row];
  const float4 uv = *reinterpret_cast<const float4*>(&uw[(size_t)uidx * EMB + e * 4]);
  const float4 pv = *reinterpret_cast<const float4*>(&iw[(size_t)pidx * EMB + e * 4]);

  float us = uv.x*uv.x + uv.y*uv.y + uv.z*uv.z + uv.w*uv.w;
  float ps = pv.x*pv.x + pv.y*pv.y + pv.z*pv.z + pv.w*pv.w;
  #pragma unroll
  for (int off = 1; off < 16; off <<= 1) {
    us += __shfl_xor(us, off);
    ps += __shfl_xor(ps, off);
  }
  const float ur = 1.0f / fmaxf(sqrtf(us), 1e-12f);
  const float pr = 1.0f / fmaxf(sqrtf(ps), 1e-12f);
  const float4 un = make_float4(uv.x*ur, uv.y*ur, uv.z*ur, uv.w*ur);
  const float4 pn = make_float4(pv.x*pr, pv.y*pr, pv.z*pr, pv.w*pr);

  ushort4 ub, pb;
  ub.x = __bfloat16_as_ushort(__float2bfloat16(un.x));
  ub.y = __bfloat16_as_ushort(__float2bfloat16(un.y));
  ub.z = __bfloat16_as_ushort(__float2bfloat16(un.z));
  ub.w = __bfloat16_as_ushort(__float2bfloat16(un.w));
  pb.x = __bfloat16_as_ushort(__float2bfloat16(pn.x));
  pb.y = __bfloat16_as_ushort(__float2bfloat16(pn.y));
  pb.z = __bfloat16_as_ushort(__float2bfloat16(pn.z));
  pb.w = __bfloat16_as_ushort(__float2bfloat16(pn.w));
  *reinterpret_cast<ushort4*>(&u_bf[(size_t)row * EMB + e * 4]) = ub;
  *reinterpret_cast<ushort4*>(&p_bf[(size_t)row * EMB + e * 4]) = pb;

  float ip = un.x*pn.x + un.y*pn.y + un.z*pn.z + un.w*pn.w;
  #pragma unroll
  for (int off = 1; off < 16; off <<= 1) ip += __shfl_xor(ip, off);

  float upv = 0.0f;
  if (e == 0) {
    const float t = ip * C5LOG2E;
    upv = logf(EXP2_HW(t) + EXP2_HW(ip * t));  // log(exp(ip/T)+exp(ip^2/T))
  }
  upv += __shfl_xor(upv, 16);
  upv += __shfl_xor(upv, 32);

  __shared__ float sred[4];
  if (lane == 0) sred[wave] = upv;
  __syncthreads();
  if (tid == 0)
    up_p[blockIdx.x] = (sred[0] + sred[1]) + (sred[2] + sred[3]);
}

// 512 blocks = 64 row-strips x 8 col-groups x 8 tiles; 64x32 half-steps,
// single-buffer B (r14/r15-proven 60-VGPR, 16B-LDS shape -> 8 blocks/CU).
// Blocks 0..31 scatter dedup bits (global bitmap) before tile work; the
// last-done block (atomic counter, r14-proven pattern) popcounts the bitmap
// and reduces all partials -> out. Saves the finalize dispatch (~2.5us) and
// halves per-block fixed costs vs 1024 blocks.
__global__ __launch_bounds__(256) void gemm_kernel(
    const __hip_bfloat16* __restrict__ U, const __hip_bfloat16* __restrict__ P,
    const int* __restrict__ user, const int* __restrict__ pos,
    const float* __restrict__ up_p, float* __restrict__ dn_p,
    unsigned int* __restrict__ bitmap, unsigned int* __restrict__ done_cnt,
    float* __restrict__ out)
{
  const int tid  = threadIdx.x;
  const int blk  = blockIdx.x;
  const int by   = blk >> 3;           // [0,64)
  const int bx0  = (blk & 7) << 3;     // 8 tiles -> 64 col-tiles
  const int wave = tid >> 6;
  const int lane = tid & 63;
  const int r0   = by * 128 + (wave >> 1) * 64;
  const int lrow = lane & 15;
  const int lk   = (lane >> 4) * 8;

  // Dedup scatter (rows blk*256 .. +255), overlaps with A-load latency.
  if (blk < 32) {
    const int i = blk * 256 + tid;
    const int u = user[i];
    const int p = pos[i];
    atomicOr(&bitmap[u >> 5], 1u << (u & 31));
    atomicOr(&bitmap[3125 + (p >> 5)], 1u << (p & 31));
  }

  short8 a[4][2];
  #pragma unroll
  for (int i = 0; i < 4; ++i)
    #pragma unroll
    for (int kk = 0; kk < 2; ++kk)
      a[i][kk] = *reinterpret_cast<const short8*>(
          &U[(size_t)(r0 + i * 16 + lrow) * EMB + kk * 32 + lk]);

  float s0 = 0.0f, s1 = 0.0f, s2 = 0.0f, s3 = 0.0f;

  #pragma unroll 1
  for (int s = 0; s < 16; ++s) {
    // step s: tile t = s>>1, half h = s&1 -> 64 rows x 32 cols
    const int c0 = (bx0 + (s >> 1)) * 128 + (wave & 1) * 64 + (s & 1) * 32;

    short8 b[2][2];
    #pragma unroll
    for (int j = 0; j < 2; ++j)
      #pragma unroll
      for (int kk = 0; kk < 2; ++kk)
        b[j][kk] = *reinterpret_cast<const short8*>(
            &P[(size_t)(c0 + j * 16 + lrow) * EMB + kk * 32 + lk]);

    f32x4 acc[4][2] = {};
    #pragma unroll
    for (int i = 0; i < 4; ++i)
      #pragma unroll
      for (int j = 0; j < 2; ++j) {
        acc[i][j] = mfma16x16x32(a[i][0], b[j][0], acc[i][j]);
        acc[i][j] = mfma16x16x32(a[i][1], b[j][1], acc[i][j]);
      }

    // exp(v/T)=2^(v*C); exp(v^2/T)=2^(v*(v*C)); |v|<=~1.
    #pragma unroll
    for (int i = 0; i < 4; ++i)
      #pragma unroll
      for (int j = 0; j < 2; ++j)
        #pragma unroll
        for (int r = 0; r < 4; ++r) {
          const float v  = acc[i][j][r];
          const float tt = v * C5LOG2E;
          if (j) { s2 += EXP2_HW(tt); s3 += EXP2_HW(v * tt); }
          else   { s0 += EXP2_HW(tt); s1 += EXP2_HW(v * tt); }
        }
  }

  float s = (s0 + s1) + (s2 + s3);
  #pragma unroll
  for (int off = 32; off; off >>= 1) s += __shfl_xor(s, off);

  __shared__ float sredf[4];
  __shared__ unsigned int is_last;
  if (lane == 0) sredf[wave] = s;
  __syncthreads();
  if (tid == 0)
    dn_p[blk] = (sredf[0] + sredf[1]) + (sredf[2] + sredf[3]);

  // ---- last-block-done: dedup popcount + final reduction ----
  __threadfence();                      // release dn_p + bitmap scatters
  if (tid == 0)
    is_last = (atomicAdd(done_cnt, 1u) == 511u) ? 1u : 0u;
  __syncthreads();
  if (!is_last) return;
  __threadfence();                      // acquire all blocks' writes

  int uc = 0, ic = 0;
  for (int i = tid; i < 3125; i += 256) uc += __popc(bitmap[i]);
  for (int i = tid; i < 3125; i += 256) ic += __popc(bitmap[3125 + i]);
  float upv = 0.0f, dnv = 0.0f;
  for (int i = tid; i < 512; i += 256) {
    upv += up_p[i];
    dnv += dn_p[i];
  }

  #pragma unroll
  for (int off = 32; off; off >>= 1) {
    upv += __shfl_xor(upv, off);
    dnv += __shfl_xor(dnv, off);
    uc  += __shfl_xor(uc, off);
    ic  += __shfl_xor(ic, off);
  }

  __shared__ float ff[2][4];
  __shared__ int   gg[2][4];
  if (lane == 0) { ff[0][wave] = upv; ff[1][wave] = dnv; gg[0][wave] = uc; gg[1][wave] = ic; }
  __syncthreads();
  if (tid == 0) {
    const float usum = (ff[0][0] + ff[0][1]) + (ff[0][2] + ff[0][3]);
    const float dsum = (ff[1][0] + ff[1][1]) + (ff[1][2] + ff[1][3]);
    const int   nu   = gg[0][0] + gg[0][1] + gg[0][2] + gg[0][3];
    const int   ni   = gg[1][0] + gg[1][1] + gg[1][2] + gg[1][3];
    out[0] = -(usum / 8192.0f);
    out[1] = logf(dsum / ((float)nu * (float)ni));
  }
}

extern "C" void kernel_launch(void* const* d_in, const int* in_sizes, int n_in,
                              void* d_out, int out_size, void* d_ws, size_t ws_size,
                              hipStream_t stream) {
  const int*   user = (const int*)d_in[0];
  const int*   pos  = (const int*)d_in[1];
  // d_in[2] = negative (unused by the reference loss)
  const float* uw   = (const float*)d_in[3];
  const float* iw   = (const float*)d_in[4];
  float* out = (float*)d_out;

  char* ws = (char*)d_ws;
  __hip_bfloat16* u_bf = (__hip_bfloat16*)(ws);
  __hip_bfloat16* p_bf = (__hip_bfloat16*)(ws + (1u << 20));
  float* up_p = (float*)(ws + (2u << 20));               // 512
  float* dn_p = up_p + 512;                              // 512
  unsigned int* bitmap   = (unsigned int*)(dn_p + 512);  // 6250 words (25 KB)
  unsigned int* done_cnt = bitmap + 6250;

  prep_kernel<<<512, 256, 0, stream>>>(user, pos, uw, iw, u_bf, p_bf,
                                       up_p, bitmap, done_cnt);
  gemm_kernel<<<512, 256, 0, stream>>>(u_bf, p_bf, user, pos,
                                       up_p, dn_p, bitmap, done_cnt, out);
}